// Round 2
// baseline (424.834 us; speedup 1.0000x reference)
//
#include <hip/hip_runtime.h>
#include <hip/hip_bf16.h>
#include <math.h>

#define L 2048
#define NH 10
#define DP 32
#define D30 30

typedef __attribute__((ext_vector_type(8))) short bf16x8;
typedef __attribute__((ext_vector_type(4))) float f32x4;

__device__ inline short f2bf(float f) {
    union { float f; unsigned u; } v; v.f = f;
    unsigned r = (v.u + 0x7FFF + ((v.u >> 16) & 1)) >> 16;
    return (short)r;
}
// pack two floats to bf16x2 (round-half-up: cheap, <=0.5 ulp)
__device__ inline unsigned pk2(float a, float b) {
    unsigned ua = __float_as_uint(a) + 0x8000u;
    unsigned ub = __float_as_uint(b) + 0x8000u;
    return (ua >> 16) | (ub & 0xFFFF0000u);
}

// K-order permutation within 64-chunks: P and Vt both use k' = (l&15)*4 + (l>>4)&3
__device__ inline int permL(int l) {
    return (l & ~63) | ((l & 15) << 2) | ((l >> 4) & 3);
}

// ---------------- Projection kernel ----------------
// og0: Wq,x -> K p0 (scaled) + V p0 + Vt'; og1/2: Wk,ax[al] -> K p1/p2 (scaled);
// og3/4: Wv,ax[al] -> V p1/p2 + Vt'.   d = 3*(c%10)+part, h = c/10.
// Kbuf is pre-scaled by (1/sqrt(10))*log2(e) so attn does pe = exp2(S*edge).
__global__ __launch_bounds__(256) void proj_kernel(
    const float* __restrict__ x, const float* __restrict__ ax,
    const float* __restrict__ wq, const float* __restrict__ bq,
    const float* __restrict__ wk, const float* __restrict__ bk,
    const float* __restrict__ wv, const float* __restrict__ bv,
    short* __restrict__ Kbuf, short* __restrict__ Vbuf, short* __restrict__ Vtbuf)
{
    __shared__ float Xs[64 * 68];    // [ci 0..63][l 0..63], stride 68 (16B-aligned)
    const int t  = threadIdx.x;
    const int l0 = blockIdx.x * 64;
    const int og = blockIdx.y;       // 0..4
    const int b  = blockIdx.z;

    const float* W; const float* bias;
    if (og == 0)      { W = wq; bias = bq; }
    else if (og <= 2) { W = wk; bias = bk; }
    else              { W = wv; bias = bv; }
    const int al = (og - 1) & 1;

    const int og2 = t >> 4;   // 0..15 : o = og2 + 16*j, j<7 covers o 0..111 >= 100
    const int lg  = t & 15;   // l = l0 + lg*4 + i

    float acc[7][4];
    #pragma unroll
    for (int j = 0; j < 7; j++)
        #pragma unroll
        for (int i = 0; i < 4; i++) acc[j][i] = 0.f;

    for (int cc = 0; cc < 4; cc++) {
        const int c0 = cc * 64;
        __syncthreads();
        {   // stage X chunk naturally (vectorized, no transpose)
            int ci = t >> 2, q = t & 3;
            const float* src = (og == 0)
                ? x  + ((size_t)(b * 256 + c0 + ci)) * L + l0
                : ax + (((size_t)(b * 256 + c0 + ci)) * 2 + al) * L + l0;
            #pragma unroll
            for (int ii = 0; ii < 4; ii++) {
                f32x4 vv = *(const f32x4*)(src + q * 16 + ii * 4);
                *(f32x4*)&Xs[ci * 68 + q * 16 + ii * 4] = vv;
            }
        }
        __syncthreads();
        #pragma unroll 4
        for (int ci4 = 0; ci4 < 16; ci4++) {
            f32x4 xr[4];
            #pragma unroll
            for (int kk = 0; kk < 4; kk++)
                xr[kk] = *(const f32x4*)&Xs[(ci4 * 4 + kk) * 68 + lg * 4];
            #pragma unroll
            for (int j = 0; j < 7; j++) {
                int o = og2 + 16 * j;
                int orow = (o < 100) ? o : 0;   // clamp: junk rows never stored
                f32x4 w4 = *(const f32x4*)(W + (size_t)orow * 256 + c0 + ci4 * 4);
                #pragma unroll
                for (int i = 0; i < 4; i++)
                    acc[j][i] += w4[0] * xr[0][i] + w4[1] * xr[1][i]
                               + w4[2] * xr[2][i] + w4[3] * xr[3][i];
            }
        }
    }

    const int part = (og == 0) ? 0 : ((og == 1 || og == 3) ? 1 : 2);
    const float KS = 0.31622776601683794f * 1.4426950408889634f;  // scale*log2e
    #pragma unroll
    for (int j = 0; j < 7; j++) {
        int o = og2 + 16 * j;
        if (o >= 100) continue;
        float bc = bias[o];
        int h = o / 10, dd = 3 * (o % 10) + part;
        size_t rowbase = ((size_t)(b * NH + h)) * L;
        size_t tbase   = ((size_t)(b * NH + h) * DP + dd) * L;
        #pragma unroll
        for (int i = 0; i < 4; i++) {
            int l = l0 + lg * 4 + i;
            float val = acc[j][i] + bc;
            if (og == 0) {
                Kbuf[(rowbase + l) * DP + dd] = f2bf(val * KS);
                short s = f2bf(val);
                Vbuf[(rowbase + l) * DP + dd] = s;
                Vtbuf[tbase + permL(l)] = s;
            } else if (og <= 2) {
                Kbuf[(rowbase + l) * DP + dd] = f2bf(val * KS);
            } else {
                short s = f2bf(val);
                Vbuf[(rowbase + l) * DP + dd] = s;
                Vtbuf[tbase + permL(l)] = s;
            }
        }
    }
}

// ---------------- Flash attention, no-max softmax, 2 heads/wave ----------------
// Scores bounded (|S*e| <~ 25 as exp2 arg) -> skip running max entirely.
// lsum accumulated per-lane, reduced once in epilogue. No __syncthreads anywhere.
__global__ __launch_bounds__(128) void attn_kernel(
    const short* __restrict__ Kbuf, const short* __restrict__ Vbuf,
    const short* __restrict__ Vtbuf, const float* __restrict__ edge,
    float* __restrict__ attbuf)
{
    __shared__ short Pl[2][2][2][16 * 72];   // [wave][dbuf][head][16 rows x 72]
    const int t    = threadIdx.x;
    const int w    = t >> 6;
    const int lane = t & 63;
    const int quad = lane >> 4;
    const int l15  = lane & 15;
    const int l0   = blockIdx.x * 32;
    const int h0   = blockIdx.y * 2;
    const int b    = blockIdx.z;
    const size_t bh0 = (size_t)(b * NH + h0);
    const size_t bh1 = bh0 + 1;

    const int lrow = l0 + w * 16 + l15;
    bf16x8 kf0 = *(const bf16x8*)(Kbuf + (bh0 * L + lrow) * DP + quad * 8);
    bf16x8 kf1 = *(const bf16x8*)(Kbuf + (bh1 * L + lrow) * DP + quad * 8);

    const int myrow = l0 + w * 16 + quad * 4;
    const float* e0 = edge + (size_t)b * L * L + (size_t)myrow * L + l15;

    float ls0[4] = {0, 0, 0, 0}, ls1[4] = {0, 0, 0, 0};
    f32x4 O00 = {0,0,0,0}, O01 = {0,0,0,0}, O10 = {0,0,0,0}, O11 = {0,0,0,0};
    const f32x4 z = {0,0,0,0};

    #pragma unroll 2
    for (int mt = 0; mt < 32; mt++) {
        const int m0 = mt * 64;
        // edge gathers first (longest latency, fully independent)
        float e[4][4];
        #pragma unroll
        for (int r = 0; r < 4; r++)
            #pragma unroll
            for (int nb = 0; nb < 4; nb++)
                e[nb][r] = e0[(size_t)r * L + m0 + nb * 16];

        f32x4 S0[4], S1[4];
        #pragma unroll
        for (int nb = 0; nb < 4; nb++) {
            bf16x8 vf = *(const bf16x8*)(Vbuf + (bh0 * L + m0 + nb * 16 + l15) * DP + quad * 8);
            S0[nb] = __builtin_amdgcn_mfma_f32_16x16x32_bf16(kf0, vf, z, 0, 0, 0);
        }
        #pragma unroll
        for (int nb = 0; nb < 4; nb++) {
            bf16x8 vf = *(const bf16x8*)(Vbuf + (bh1 * L + m0 + nb * 16 + l15) * DP + quad * 8);
            S1[nb] = __builtin_amdgcn_mfma_f32_16x16x32_bf16(kf1, vf, z, 0, 0, 0);
        }

        short* P0 = &Pl[w][mt & 1][0][0];
        short* P1 = &Pl[w][mt & 1][1][0];
        #pragma unroll
        for (int r = 0; r < 4; r++) {
            float p0 = __builtin_amdgcn_exp2f(S0[0][r] * e[0][r]);
            float p1 = __builtin_amdgcn_exp2f(S0[1][r] * e[1][r]);
            float p2 = __builtin_amdgcn_exp2f(S0[2][r] * e[2][r]);
            float p3 = __builtin_amdgcn_exp2f(S0[3][r] * e[3][r]);
            ls0[r] += (p0 + p1) + (p2 + p3);
            uint2 u; u.x = pk2(p0, p1); u.y = pk2(p2, p3);
            *(uint2*)&P0[(quad * 4 + r) * 72 + l15 * 4] = u;   // k' = l15*4+nb
        }
        #pragma unroll
        for (int r = 0; r < 4; r++) {
            float p0 = __builtin_amdgcn_exp2f(S1[0][r] * e[0][r]);
            float p1 = __builtin_amdgcn_exp2f(S1[1][r] * e[1][r]);
            float p2 = __builtin_amdgcn_exp2f(S1[2][r] * e[2][r]);
            float p3 = __builtin_amdgcn_exp2f(S1[3][r] * e[3][r]);
            ls1[r] += (p0 + p1) + (p2 + p3);
            uint2 u; u.x = pk2(p0, p1); u.y = pk2(p2, p3);
            *(uint2*)&P1[(quad * 4 + r) * 72 + l15 * 4] = u;
        }

        #pragma unroll
        for (int ks = 0; ks < 2; ks++) {
            bf16x8 a0  = *(const bf16x8*)&P0[l15 * 72 + ks * 32 + quad * 8];
            bf16x8 b00 = *(const bf16x8*)(Vtbuf + (bh0 * DP + l15)      * L + m0 + ks * 32 + quad * 8);
            bf16x8 b01 = *(const bf16x8*)(Vtbuf + (bh0 * DP + 16 + l15) * L + m0 + ks * 32 + quad * 8);
            O00 = __builtin_amdgcn_mfma_f32_16x16x32_bf16(a0, b00, O00, 0, 0, 0);
            O01 = __builtin_amdgcn_mfma_f32_16x16x32_bf16(a0, b01, O01, 0, 0, 0);
            bf16x8 a1  = *(const bf16x8*)&P1[l15 * 72 + ks * 32 + quad * 8];
            bf16x8 b10 = *(const bf16x8*)(Vtbuf + (bh1 * DP + l15)      * L + m0 + ks * 32 + quad * 8);
            bf16x8 b11 = *(const bf16x8*)(Vtbuf + (bh1 * DP + 16 + l15) * L + m0 + ks * 32 + quad * 8);
            O10 = __builtin_amdgcn_mfma_f32_16x16x32_bf16(a1, b10, O10, 0, 0, 0);
            O11 = __builtin_amdgcn_mfma_f32_16x16x32_bf16(a1, b11, O11, 0, 0, 0);
        }
    }

    // epilogue: lane-reduce lsum (within quad), normalize, store torch-view layout
    float* ab = attbuf + (size_t)b * (NH * L * D30);
    #pragma unroll
    for (int r = 0; r < 4; r++) {
        float s0 = ls0[r];
        s0 += __shfl_xor(s0, 1); s0 += __shfl_xor(s0, 2);
        s0 += __shfl_xor(s0, 4); s0 += __shfl_xor(s0, 8);
        float s1 = ls1[r];
        s1 += __shfl_xor(s1, 1); s1 += __shfl_xor(s1, 2);
        s1 += __shfl_xor(s1, 4); s1 += __shfl_xor(s1, 8);
        float inv0 = 1.f / s0, inv1 = 1.f / s1;
        int l = myrow + r;
        size_t base0 = (size_t)h0 * (L * D30) + (size_t)l * D30;
        size_t base1 = base0 + (size_t)(L * D30);
        ab[base0 + l15] = O00[r] * inv0;
        ab[base1 + l15] = O10[r] * inv1;
        if (l15 < 14) {
            ab[base0 + 16 + l15] = O01[r] * inv0;
            ab[base1 + 16 + l15] = O11[r] * inv1;
        }
    }
}

// ---------------- Output projection ----------------
// out[b,o,m] = bo[o] + sum_c wo[o,c] * ab[c*L + m], ab = attbuf viewed [300][2048]
__global__ __launch_bounds__(256) void out_kernel(
    const float* __restrict__ attbuf, const float* __restrict__ wo,
    const float* __restrict__ bo, float* __restrict__ out)
{
    const int t  = threadIdx.x;
    const int og = t >> 4;            // o = o0 + og*4 + j
    const int mg = t & 15;            // m = m0 + mg*4 + i
    const int m0 = blockIdx.x * 64;
    const int o0 = blockIdx.y * 64;
    const int b  = blockIdx.z;
    const float* ab = attbuf + (size_t)b * (NH * L * D30);

    f32x4 acc[4] = {{0,0,0,0},{0,0,0,0},{0,0,0,0},{0,0,0,0}};

    for (int c = 0; c < 300; c += 4) {
        f32x4 a[4];
        #pragma unroll
        for (int cc = 0; cc < 4; cc++)
            a[cc] = *(const f32x4*)(ab + (size_t)(c + cc) * L + m0 + mg * 4);
        #pragma unroll
        for (int j = 0; j < 4; j++) {
            int o = o0 + og * 4 + j;
            f32x4 w4 = *(const f32x4*)(wo + (size_t)o * 300 + c);
            acc[j] += w4[0] * a[0] + w4[1] * a[1] + w4[2] * a[2] + w4[3] * a[3];
        }
    }
    #pragma unroll
    for (int j = 0; j < 4; j++) {
        int o = o0 + og * 4 + j;
        f32x4 r = acc[j] + bo[o];
        *(f32x4*)(out + ((size_t)(b * 256 + o)) * L + m0 + mg * 4) = r;
    }
}

extern "C" void kernel_launch(void* const* d_in, const int* in_sizes, int n_in,
                              void* d_out, int out_size, void* d_ws, size_t ws_size,
                              hipStream_t stream) {
    const float* x    = (const float*)d_in[0];
    const float* ax   = (const float*)d_in[1];
    const float* edge = (const float*)d_in[2];
    const float* wq   = (const float*)d_in[3];
    const float* bq   = (const float*)d_in[4];
    const float* wk   = (const float*)d_in[5];
    const float* bk   = (const float*)d_in[6];
    const float* wv   = (const float*)d_in[7];
    const float* bv   = (const float*)d_in[8];
    const float* wo   = (const float*)d_in[9];
    const float* bo   = (const float*)d_in[10];
    float* out = (float*)d_out;

    const size_t KB = (size_t)4 * NH * L * DP * 2;   // 5,242,880 B per bf16 buffer
    char* ws = (char*)d_ws;
    short* Kbuf   = (short*)ws;
    short* Vbuf   = (short*)(ws + KB);
    short* Vtbuf  = (short*)(ws + 2 * KB);
    float* attbuf = (float*)(ws + 3 * KB);           // 9,830,400 B fp32
    if (ws_size < 3 * KB + (size_t)4 * NH * L * D30 * 4) return;

    hipMemsetAsync(ws, 0, 3 * KB, stream);           // zero pad cols d=30,31

    proj_kernel<<<dim3(32, 5, 4), 256, 0, stream>>>(x, ax, wq, bq, wk, bk, wv, bv,
                                                    Kbuf, Vbuf, Vtbuf);
    attn_kernel<<<dim3(64, 5, 4), 128, 0, stream>>>(Kbuf, Vbuf, Vtbuf, edge, attbuf);
    out_kernel<<<dim3(32, 4, 4), 256, 0, stream>>>(attbuf, wo, bo, out);
}

// Round 3
// 295.125 us; speedup vs baseline: 1.4395x; 1.4395x over previous
//
#include <hip/hip_runtime.h>
#include <hip/hip_bf16.h>
#include <math.h>

#define L 2048
#define NH 10
#define DP 32
#define D30 30

typedef __attribute__((ext_vector_type(8))) short bf16x8;
typedef __attribute__((ext_vector_type(4))) float f32x4;

__device__ inline short f2bf(float f) {
    union { float f; unsigned u; } v; v.f = f;
    unsigned r = (v.u + 0x7FFF + ((v.u >> 16) & 1)) >> 16;
    return (short)r;
}
// pack two floats to bf16x2 (round-half-up)
__device__ inline unsigned pk2(float a, float b) {
    unsigned ua = __float_as_uint(a) + 0x8000u;
    unsigned ub = __float_as_uint(b) + 0x8000u;
    return (ua >> 16) | (ub & 0xFFFF0000u);
}
// K-order permutation within 64-chunks (shared by P-tile and Vt layout)
__device__ inline int permL(int l) {
    return (l & ~63) | ((l & 15) << 2) | ((l >> 4) & 3);
}

#define GLD16(g, l) __builtin_amdgcn_global_load_lds( \
    (__attribute__((address_space(1))) void*)(g),     \
    (__attribute__((address_space(3))) void*)(l), 16, 0, 0)

// ---------------- Projection kernel (bf16 MFMA) ----------------
// Per block: C[112 o x 64 l] = W[112x256] * X[256x64], K-chunked by 64.
// og0: Wq,x -> K(scaled)+V+Vt; og1/2: Wk,ax[al] -> K; og3/4: Wv,ax[al] -> V+Vt.
__global__ __launch_bounds__(256) void proj_kernel(
    const float* __restrict__ x, const float* __restrict__ ax,
    const float* __restrict__ wq, const float* __restrict__ bq,
    const float* __restrict__ wk, const float* __restrict__ bk,
    const float* __restrict__ wv, const float* __restrict__ bv,
    short* __restrict__ Kbuf, short* __restrict__ Vbuf, short* __restrict__ Vtbuf)
{
    __shared__ __align__(16) short Wl[112 * 72];   // [o][64c], stride 72 (pad)
    __shared__ __align__(16) short XT[64 * 72];    // [l][64c], stride 72
    const int t  = threadIdx.x;
    const int l0 = blockIdx.x * 64;
    const int og = blockIdx.y;       // 0..4
    const int b  = blockIdx.z;

    const float* W; const float* bias;
    if (og == 0)      { W = wq; bias = bq; }
    else if (og <= 2) { W = wk; bias = bk; }
    else              { W = wv; bias = bv; }
    const int al = (og - 1) & 1;

    const int wid  = t >> 6;
    const int lane = t & 63;
    const int quad = lane >> 4;
    const int l15  = lane & 15;

    f32x4 acc[7];
    #pragma unroll
    for (int ot = 0; ot < 7; ot++) acc[ot] = (f32x4){0,0,0,0};

    const int cq = (t & 15) * 4;    // c-quad for X staging
    const int lq = (t >> 4) * 4;    // l-quad for X staging
    const size_t rs = (og == 0) ? (size_t)L : (size_t)(2 * L);  // c-row stride

    for (int cc = 0; cc < 4; cc++) {
        const int c0 = cc * 64;
        __syncthreads();
        // stage W chunk [112 x 64] fp32 -> bf16 (rows >=100 zero)
        #pragma unroll
        for (int it = 0; it < 7; it++) {
            int kk = (t + it * 256) * 4;
            int o = kk >> 6, c = kk & 63;
            f32x4 v = {0, 0, 0, 0};
            if (o < 100) v = *(const f32x4*)(W + (size_t)o * 256 + c0 + c);
            uint2 u; u.x = pk2(v[0], v[1]); u.y = pk2(v[2], v[3]);
            *(uint2*)&Wl[o * 72 + c] = u;
        }
        // stage X^T chunk [64 l x 64 c] via 4x4 register transpose
        {
            const float* src = (og == 0)
                ? x  + ((size_t)(b * 256 + c0 + cq)) * L + l0 + lq
                : ax + (((size_t)(b * 256 + c0 + cq)) * 2 + al) * L + l0 + lq;
            f32x4 r0 = *(const f32x4*)(src);
            f32x4 r1 = *(const f32x4*)(src + rs);
            f32x4 r2 = *(const f32x4*)(src + 2 * rs);
            f32x4 r3 = *(const f32x4*)(src + 3 * rs);
            #pragma unroll
            for (int i = 0; i < 4; i++) {
                uint2 u; u.x = pk2(r0[i], r1[i]); u.y = pk2(r2[i], r3[i]);
                *(uint2*)&XT[(lq + i) * 72 + cq] = u;
            }
        }
        __syncthreads();
        #pragma unroll
        for (int ks = 0; ks < 2; ks++) {
            bf16x8 bfrag = *(const bf16x8*)&XT[(wid * 16 + l15) * 72 + ks * 32 + quad * 8];
            #pragma unroll
            for (int ot = 0; ot < 7; ot++) {
                bf16x8 afrag = *(const bf16x8*)&Wl[(ot * 16 + l15) * 72 + ks * 32 + quad * 8];
                acc[ot] = __builtin_amdgcn_mfma_f32_16x16x32_bf16(afrag, bfrag, acc[ot], 0, 0, 0);
            }
        }
    }

    // epilogue: C col = lane&15 -> l, row = quad*4+r -> o
    const int part = (og == 0) ? 0 : ((og == 1 || og == 3) ? 1 : 2);
    const float KS = 0.31622776601683794f * 1.4426950408889634f;  // scale*log2e
    const int l = l0 + wid * 16 + l15;
    #pragma unroll
    for (int ot = 0; ot < 7; ot++) {
        #pragma unroll
        for (int r = 0; r < 4; r++) {
            int o = ot * 16 + quad * 4 + r;
            if (o >= 100) continue;
            float val = acc[ot][r] + bias[o];
            int h = o / 10, dd = 3 * (o % 10) + part;
            size_t rowb = ((size_t)(b * NH + h)) * L;
            size_t tb   = ((size_t)(b * NH + h) * DP + dd) * L;
            if (og == 0) {
                Kbuf[(rowb + l) * DP + dd] = f2bf(val * KS);
                short s = f2bf(val);
                Vbuf[(rowb + l) * DP + dd] = s;
                Vtbuf[tb + permL(l)] = s;
            } else if (og <= 2) {
                Kbuf[(rowb + l) * DP + dd] = f2bf(val * KS);
            } else {
                short s = f2bf(val);
                Vbuf[(rowb + l) * DP + dd] = s;
                Vtbuf[tb + permL(l)] = s;
            }
        }
    }
}

// ---------------- Flash attention: LDS-staged tiles, 4 waves, 2 heads ----------------
// Block: 64 q-rows (4 waves x 16), heads (h0,h0+1), m-range of L/npart.
// V/Vt tiles staged via global_load_lds with XOR granule swizzle (<=2-way conflicts).
__global__ __launch_bounds__(256, 4) void attn_kernel(
    const short* __restrict__ K, const short* __restrict__ V,
    const short* __restrict__ Vt, const float* __restrict__ edge,
    float* __restrict__ Opart, float* __restrict__ lsums, int npart)
{
    __shared__ __align__(16) short Vl[2][64 * 32];    // [head][m][d-granule swizzled]
    __shared__ __align__(16) short Vtl[2][32 * 64];   // [head][d][m-granule swizzled]
    __shared__ __align__(16) short Pm[4][2][16 * 72]; // per-wave private P tiles
    const int t    = threadIdx.x;
    const int wid  = t >> 6;
    const int lane = t & 63;
    const int quad = lane >> 4;
    const int l15  = lane & 15;
    const int l0   = blockIdx.x * 64;
    const int h0   = blockIdx.y * 2;
    const int b    = blockIdx.z & 3;
    const int mz   = blockIdx.z >> 2;
    const size_t bh0 = (size_t)(b * NH + h0), bh1 = bh0 + 1;
    const int mbase = mz * (L / npart);
    const int nit   = (L / npart) / 64;

    const int lrow = l0 + wid * 16 + l15;
    bf16x8 kf0 = *(const bf16x8*)(K + (bh0 * L + lrow) * DP + quad * 8);
    bf16x8 kf1 = *(const bf16x8*)(K + (bh1 * L + lrow) * DP + quad * 8);

    const int myrow = l0 + wid * 16 + quad * 4;
    const float* e0 = edge + (size_t)b * L * L + (size_t)myrow * L + l15;

    float ls0[4] = {0, 0, 0, 0}, ls1[4] = {0, 0, 0, 0};
    f32x4 O00 = {0,0,0,0}, O01 = {0,0,0,0}, O10 = {0,0,0,0}, O11 = {0,0,0,0};
    const f32x4 z = {0,0,0,0};

    const int sh = wid & 1;                 // head this wave stages
    const size_t sbh = bh0 + sh;

    for (int mt = 0; mt < nit; mt++) {
        const int m0 = mbase + mt * 64;
        __syncthreads();                    // prior reads done before overwrite
        if (wid < 2) {                      // stage V tile [64m x 32d] for head sh
            const short* gb = V + (sbh * L + m0) * DP;
            #pragma unroll
            for (int k = 0; k < 4; k++) {
                int m = k * 16 + (lane >> 2);
                int g = (lane & 3) ^ ((lane >> 3) & 3);   // slot^((m>>1)&3)
                GLD16(gb + m * DP + g * 8, &Vl[sh][k * 16 * 32]);
            }
        } else {                            // stage Vt tile [32d x 64m] for head sh
            const short* gb = Vt + sbh * DP * L + m0;
            #pragma unroll
            for (int k = 0; k < 4; k++) {
                int d = k * 8 + (lane >> 3);
                int g = (lane & 7) ^ ((lane >> 3) & 7);   // slot^(d&7)
                GLD16(gb + (size_t)d * L + g * 8, &Vtl[sh][k * 8 * 64]);
            }
        }
        // edge gathers (drain together with tiles at next barrier)
        float e[4][4];
        #pragma unroll
        for (int r = 0; r < 4; r++)
            #pragma unroll
            for (int nb = 0; nb < 4; nb++)
                e[nb][r] = e0[(size_t)r * L + m0 + nb * 16];
        __syncthreads();                    // tiles + edge ready

        // QK^T from LDS V tiles
        f32x4 S0[4], S1[4];
        #pragma unroll
        for (int nb = 0; nb < 4; nb++) {
            int sw = (quad ^ ((l15 >> 1) & 3)) * 8;       // granule swizzle
            bf16x8 vf0 = *(const bf16x8*)&Vl[0][(nb * 16 + l15) * 32 + sw];
            bf16x8 vf1 = *(const bf16x8*)&Vl[1][(nb * 16 + l15) * 32 + sw];
            S0[nb] = __builtin_amdgcn_mfma_f32_16x16x32_bf16(kf0, vf0, z, 0, 0, 0);
            S1[nb] = __builtin_amdgcn_mfma_f32_16x16x32_bf16(kf1, vf1, z, 0, 0, 0);
        }

        short* P0 = &Pm[wid][0][0];
        short* P1 = &Pm[wid][1][0];
        #pragma unroll
        for (int r = 0; r < 4; r++) {
            float p0 = __builtin_amdgcn_exp2f(S0[0][r] * e[0][r]);
            float p1 = __builtin_amdgcn_exp2f(S0[1][r] * e[1][r]);
            float p2 = __builtin_amdgcn_exp2f(S0[2][r] * e[2][r]);
            float p3 = __builtin_amdgcn_exp2f(S0[3][r] * e[3][r]);
            ls0[r] += (p0 + p1) + (p2 + p3);
            uint2 u; u.x = pk2(p0, p1); u.y = pk2(p2, p3);
            *(uint2*)&P0[(quad * 4 + r) * 72 + l15 * 4] = u;   // k' = l15*4+nb
        }
        #pragma unroll
        for (int r = 0; r < 4; r++) {
            float p0 = __builtin_amdgcn_exp2f(S1[0][r] * e[0][r]);
            float p1 = __builtin_amdgcn_exp2f(S1[1][r] * e[1][r]);
            float p2 = __builtin_amdgcn_exp2f(S1[2][r] * e[2][r]);
            float p3 = __builtin_amdgcn_exp2f(S1[3][r] * e[3][r]);
            ls1[r] += (p0 + p1) + (p2 + p3);
            uint2 u; u.x = pk2(p0, p1); u.y = pk2(p2, p3);
            *(uint2*)&P1[(quad * 4 + r) * 72 + l15 * 4] = u;
        }

        // PV from P-LDS (A) and Vt-LDS (B)
        const int svt = ((l15 & 7) * 8);    // d-dependent swizzle base (xor on G)
        #pragma unroll
        for (int ks = 0; ks < 2; ks++) {
            int G = ks * 4 + quad;
            int go = (G ^ (l15 & 7)) * 8;
            bf16x8 a0  = *(const bf16x8*)&P0[l15 * 72 + ks * 32 + quad * 8];
            bf16x8 b00 = *(const bf16x8*)&Vtl[0][l15 * 64 + go];
            bf16x8 b01 = *(const bf16x8*)&Vtl[0][(16 + l15) * 64 + go];
            O00 = __builtin_amdgcn_mfma_f32_16x16x32_bf16(a0, b00, O00, 0, 0, 0);
            O01 = __builtin_amdgcn_mfma_f32_16x16x32_bf16(a0, b01, O01, 0, 0, 0);
            bf16x8 a1  = *(const bf16x8*)&P1[l15 * 72 + ks * 32 + quad * 8];
            bf16x8 b10 = *(const bf16x8*)&Vtl[1][l15 * 64 + go];
            bf16x8 b11 = *(const bf16x8*)&Vtl[1][(16 + l15) * 64 + go];
            O10 = __builtin_amdgcn_mfma_f32_16x16x32_bf16(a1, b10, O10, 0, 0, 0);
            O11 = __builtin_amdgcn_mfma_f32_16x16x32_bf16(a1, b11, O11, 0, 0, 0);
        }
        (void)svt;
    }

    // epilogue: write UNNORMALIZED O partial + lsum
    float* ab  = Opart + (size_t)mz * 2457600 + (size_t)b * 614400;
    float* lsp = lsums + (size_t)mz * 81920;
    #pragma unroll
    for (int r = 0; r < 4; r++) {
        float s0 = ls0[r];
        s0 += __shfl_xor(s0, 1); s0 += __shfl_xor(s0, 2);
        s0 += __shfl_xor(s0, 4); s0 += __shfl_xor(s0, 8);
        float s1 = ls1[r];
        s1 += __shfl_xor(s1, 1); s1 += __shfl_xor(s1, 2);
        s1 += __shfl_xor(s1, 4); s1 += __shfl_xor(s1, 8);
        int lr = myrow + r;
        if (l15 == 0) {
            lsp[bh0 * L + lr] = s0;
            lsp[bh1 * L + lr] = s1;
        }
        size_t base0 = (size_t)h0 * 61440 + (size_t)lr * D30;
        ab[base0 + l15] = O00[r];
        ab[base0 + 61440 + l15] = O10[r];
        if (l15 < 14) {
            ab[base0 + 16 + l15] = O01[r];
            ab[base0 + 61440 + 16 + l15] = O11[r];
        }
    }
}

// ---------------- Combine partials + normalize (in-place on P0) ----------------
__global__ __launch_bounds__(256) void combine_kernel(
    float* __restrict__ P0, const float* __restrict__ lsums, int npart)
{
    int i = blockIdx.x * 256 + threadIdx.x;   // 2,457,600 exact
    float v = P0[i];
    int j = i / 30;
    float s = lsums[j];
    if (npart == 2) { v += P0[2457600 + i]; s += lsums[81920 + j]; }
    P0[i] = v / s;
}

// ---------------- Output projection (fp32) ----------------
__global__ __launch_bounds__(256) void out_kernel(
    const float* __restrict__ attbuf, const float* __restrict__ wo,
    const float* __restrict__ bo, float* __restrict__ out)
{
    const int t  = threadIdx.x;
    const int og = t >> 4;            // o = o0 + og*4 + j
    const int mg = t & 15;            // m = m0 + mg*2
    const int m0 = blockIdx.x * 32;
    const int o0 = blockIdx.y * 64;
    const int b  = blockIdx.z;
    const float* ab = attbuf + (size_t)b * 614400;

    float2 acc[4] = {{0,0},{0,0},{0,0},{0,0}};
    for (int c = 0; c < 300; c += 4) {
        float2 a[4];
        #pragma unroll
        for (int cc = 0; cc < 4; cc++)
            a[cc] = *(const float2*)(ab + (size_t)(c + cc) * L + m0 + mg * 2);
        #pragma unroll
        for (int j = 0; j < 4; j++) {
            int o = o0 + og * 4 + j;
            f32x4 w4 = *(const f32x4*)(wo + (size_t)o * 300 + c);
            acc[j].x += w4[0]*a[0].x + w4[1]*a[1].x + w4[2]*a[2].x + w4[3]*a[3].x;
            acc[j].y += w4[0]*a[0].y + w4[1]*a[1].y + w4[2]*a[2].y + w4[3]*a[3].y;
        }
    }
    #pragma unroll
    for (int j = 0; j < 4; j++) {
        int o = o0 + og * 4 + j;
        float bb = bo[o];
        float2 r = {acc[j].x + bb, acc[j].y + bb};
        *(float2*)(out + ((size_t)(b * 256 + o)) * L + m0 + mg * 2) = r;
    }
}

extern "C" void kernel_launch(void* const* d_in, const int* in_sizes, int n_in,
                              void* d_out, int out_size, void* d_ws, size_t ws_size,
                              hipStream_t stream) {
    const float* x    = (const float*)d_in[0];
    const float* ax   = (const float*)d_in[1];
    const float* edge = (const float*)d_in[2];
    const float* wq   = (const float*)d_in[3];
    const float* bq   = (const float*)d_in[4];
    const float* wk   = (const float*)d_in[5];
    const float* bk   = (const float*)d_in[6];
    const float* wv   = (const float*)d_in[7];
    const float* bv   = (const float*)d_in[8];
    const float* wo   = (const float*)d_in[9];
    const float* bo   = (const float*)d_in[10];
    float* out = (float*)d_out;

    const size_t KB = (size_t)4 * NH * L * DP * 2;   // 5,242,880 per bf16 buffer
    char* ws = (char*)d_ws;
    short* Kbuf  = (short*)ws;
    short* Vbuf  = (short*)(ws + KB);
    short* Vtbuf = (short*)(ws + 2 * KB);
    float* P0    = (float*)(ws + 3 * KB);            // partial O / attbuf (9,830,400 B each)
    const size_t PSZ = (size_t)2457600 * 4;
    const size_t LSZ = (size_t)81920 * 4;
    int npart = (ws_size >= 3 * KB + 2 * PSZ + 2 * LSZ) ? 2 : 1;
    float* lsums = (float*)(ws + 3 * KB + (size_t)npart * PSZ);
    if (ws_size < 3 * KB + PSZ + LSZ) return;

    hipMemsetAsync(ws, 0, 3 * KB, stream);           // zero pad cols d=30,31

    proj_kernel<<<dim3(32, 5, 4), 256, 0, stream>>>(x, ax, wq, bq, wk, bk, wv, bv,
                                                    Kbuf, Vbuf, Vtbuf);
    attn_kernel<<<dim3(32, 5, 4 * npart), 256, 0, stream>>>(Kbuf, Vbuf, Vtbuf, edge,
                                                            P0, lsums, npart);
    combine_kernel<<<dim3(9600), 256, 0, stream>>>(P0, lsums, npart);
    out_kernel<<<dim3(64, 4, 4), 256, 0, stream>>>(P0, wo, bo, out);
}

// Round 4
// 229.161 us; speedup vs baseline: 1.8539x; 1.2878x over previous
//
#include <hip/hip_runtime.h>
#include <hip/hip_bf16.h>
#include <math.h>

#define L 2048
#define NH 10
#define DP 32
#define D30 30

typedef __attribute__((ext_vector_type(8))) short bf16x8;
typedef __attribute__((ext_vector_type(4))) float f32x4;

__device__ inline short f2bf(float f) {
    union { float f; unsigned u; } v; v.f = f;
    unsigned r = (v.u + 0x7FFF + ((v.u >> 16) & 1)) >> 16;
    return (short)r;
}
// pack two floats to bf16x2 (round-half-up)
__device__ inline unsigned pk2(float a, float b) {
    unsigned ua = __float_as_uint(a) + 0x8000u;
    unsigned ub = __float_as_uint(b) + 0x8000u;
    return (ua >> 16) | (ub & 0xFFFF0000u);
}
// K-order permutation within 64-chunks (shared by P-tile and Vt layout)
__device__ inline int permL(int l) {
    return (l & ~63) | ((l & 15) << 2) | ((l >> 4) & 3);
}

#define GLD16(g, l) __builtin_amdgcn_global_load_lds( \
    (__attribute__((address_space(1))) void*)(g),     \
    (__attribute__((address_space(3))) void*)(l), 16, 0, 0)

// ---------------- Projection kernel (bf16 MFMA) ----------------
__global__ __launch_bounds__(256) void proj_kernel(
    const float* __restrict__ x, const float* __restrict__ ax,
    const float* __restrict__ wq, const float* __restrict__ bq,
    const float* __restrict__ wk, const float* __restrict__ bk,
    const float* __restrict__ wv, const float* __restrict__ bv,
    short* __restrict__ Kbuf, short* __restrict__ Vbuf, short* __restrict__ Vtbuf)
{
    __shared__ __align__(16) short Wl[112 * 72];   // [o][64c], stride 72 (pad)
    __shared__ __align__(16) short XT[64 * 72];    // [l][64c], stride 72
    const int t  = threadIdx.x;
    const int l0 = blockIdx.x * 64;
    const int og = blockIdx.y;       // 0..4
    const int b  = blockIdx.z;

    const float* W; const float* bias;
    if (og == 0)      { W = wq; bias = bq; }
    else if (og <= 2) { W = wk; bias = bk; }
    else              { W = wv; bias = bv; }
    const int al = (og - 1) & 1;

    const int wid  = t >> 6;
    const int lane = t & 63;
    const int quad = lane >> 4;
    const int l15  = lane & 15;

    f32x4 acc[7];
    #pragma unroll
    for (int ot = 0; ot < 7; ot++) acc[ot] = (f32x4){0,0,0,0};

    const int cq = (t & 15) * 4;    // c-quad for X staging
    const int lq = (t >> 4) * 4;    // l-quad for X staging
    const size_t rs = (og == 0) ? (size_t)L : (size_t)(2 * L);  // c-row stride

    for (int cc = 0; cc < 4; cc++) {
        const int c0 = cc * 64;
        __syncthreads();
        #pragma unroll
        for (int it = 0; it < 7; it++) {
            int kk = (t + it * 256) * 4;
            int o = kk >> 6, c = kk & 63;
            f32x4 v = {0, 0, 0, 0};
            if (o < 100) v = *(const f32x4*)(W + (size_t)o * 256 + c0 + c);
            uint2 u; u.x = pk2(v[0], v[1]); u.y = pk2(v[2], v[3]);
            *(uint2*)&Wl[o * 72 + c] = u;
        }
        {
            const float* src = (og == 0)
                ? x  + ((size_t)(b * 256 + c0 + cq)) * L + l0 + lq
                : ax + (((size_t)(b * 256 + c0 + cq)) * 2 + al) * L + l0 + lq;
            f32x4 r0 = *(const f32x4*)(src);
            f32x4 r1 = *(const f32x4*)(src + rs);
            f32x4 r2 = *(const f32x4*)(src + 2 * rs);
            f32x4 r3 = *(const f32x4*)(src + 3 * rs);
            #pragma unroll
            for (int i = 0; i < 4; i++) {
                uint2 u; u.x = pk2(r0[i], r1[i]); u.y = pk2(r2[i], r3[i]);
                *(uint2*)&XT[(lq + i) * 72 + cq] = u;
            }
        }
        __syncthreads();
        #pragma unroll
        for (int ks = 0; ks < 2; ks++) {
            bf16x8 bfrag = *(const bf16x8*)&XT[(wid * 16 + l15) * 72 + ks * 32 + quad * 8];
            #pragma unroll
            for (int ot = 0; ot < 7; ot++) {
                bf16x8 afrag = *(const bf16x8*)&Wl[(ot * 16 + l15) * 72 + ks * 32 + quad * 8];
                acc[ot] = __builtin_amdgcn_mfma_f32_16x16x32_bf16(afrag, bfrag, acc[ot], 0, 0, 0);
            }
        }
    }

    const int part = (og == 0) ? 0 : ((og == 1 || og == 3) ? 1 : 2);
    const float KS = 0.31622776601683794f * 1.4426950408889634f;  // scale*log2e
    const int l = l0 + wid * 16 + l15;
    #pragma unroll
    for (int ot = 0; ot < 7; ot++) {
        #pragma unroll
        for (int r = 0; r < 4; r++) {
            int o = ot * 16 + quad * 4 + r;
            if (o >= 100) continue;
            float val = acc[ot][r] + bias[o];
            int h = o / 10, dd = 3 * (o % 10) + part;
            size_t rowb = ((size_t)(b * NH + h)) * L;
            size_t tb   = ((size_t)(b * NH + h) * DP + dd) * L;
            if (og == 0) {
                Kbuf[(rowb + l) * DP + dd] = f2bf(val * KS);
                short s = f2bf(val);
                Vbuf[(rowb + l) * DP + dd] = s;
                Vtbuf[tb + permL(l)] = s;
            } else if (og <= 2) {
                Kbuf[(rowb + l) * DP + dd] = f2bf(val * KS);
            } else {
                short s = f2bf(val);
                Vbuf[(rowb + l) * DP + dd] = s;
                Vtbuf[tb + permL(l)] = s;
            }
        }
    }
}

// ---------------- Flash attention (unchanged from r3) ----------------
__global__ __launch_bounds__(256, 4) void attn_kernel(
    const short* __restrict__ K, const short* __restrict__ V,
    const short* __restrict__ Vt, const float* __restrict__ edge,
    float* __restrict__ Opart, float* __restrict__ lsums, int npart)
{
    __shared__ __align__(16) short Vl[2][64 * 32];
    __shared__ __align__(16) short Vtl[2][32 * 64];
    __shared__ __align__(16) short Pm[4][2][16 * 72];
    const int t    = threadIdx.x;
    const int wid  = t >> 6;
    const int lane = t & 63;
    const int quad = lane >> 4;
    const int l15  = lane & 15;
    const int l0   = blockIdx.x * 64;
    const int h0   = blockIdx.y * 2;
    const int b    = blockIdx.z & 3;
    const int mz   = blockIdx.z >> 2;
    const size_t bh0 = (size_t)(b * NH + h0), bh1 = bh0 + 1;
    const int mbase = mz * (L / npart);
    const int nit   = (L / npart) / 64;

    const int lrow = l0 + wid * 16 + l15;
    bf16x8 kf0 = *(const bf16x8*)(K + (bh0 * L + lrow) * DP + quad * 8);
    bf16x8 kf1 = *(const bf16x8*)(K + (bh1 * L + lrow) * DP + quad * 8);

    const int myrow = l0 + wid * 16 + quad * 4;
    const float* e0 = edge + (size_t)b * L * L + (size_t)myrow * L + l15;

    float ls0[4] = {0, 0, 0, 0}, ls1[4] = {0, 0, 0, 0};
    f32x4 O00 = {0,0,0,0}, O01 = {0,0,0,0}, O10 = {0,0,0,0}, O11 = {0,0,0,0};
    const f32x4 z = {0,0,0,0};

    const int sh = wid & 1;
    const size_t sbh = bh0 + sh;

    for (int mt = 0; mt < nit; mt++) {
        const int m0 = mbase + mt * 64;
        __syncthreads();
        if (wid < 2) {
            const short* gb = V + (sbh * L + m0) * DP;
            #pragma unroll
            for (int k = 0; k < 4; k++) {
                int m = k * 16 + (lane >> 2);
                int g = (lane & 3) ^ ((lane >> 3) & 3);
                GLD16(gb + m * DP + g * 8, &Vl[sh][k * 16 * 32]);
            }
        } else {
            const short* gb = Vt + sbh * DP * L + m0;
            #pragma unroll
            for (int k = 0; k < 4; k++) {
                int d = k * 8 + (lane >> 3);
                int g = (lane & 7) ^ ((lane >> 3) & 7);
                GLD16(gb + (size_t)d * L + g * 8, &Vtl[sh][k * 8 * 64]);
            }
        }
        float e[4][4];
        #pragma unroll
        for (int r = 0; r < 4; r++)
            #pragma unroll
            for (int nb = 0; nb < 4; nb++)
                e[nb][r] = e0[(size_t)r * L + m0 + nb * 16];
        __syncthreads();

        f32x4 S0[4], S1[4];
        #pragma unroll
        for (int nb = 0; nb < 4; nb++) {
            int sw = (quad ^ ((l15 >> 1) & 3)) * 8;
            bf16x8 vf0 = *(const bf16x8*)&Vl[0][(nb * 16 + l15) * 32 + sw];
            bf16x8 vf1 = *(const bf16x8*)&Vl[1][(nb * 16 + l15) * 32 + sw];
            S0[nb] = __builtin_amdgcn_mfma_f32_16x16x32_bf16(kf0, vf0, z, 0, 0, 0);
            S1[nb] = __builtin_amdgcn_mfma_f32_16x16x32_bf16(kf1, vf1, z, 0, 0, 0);
        }

        short* P0 = &Pm[wid][0][0];
        short* P1 = &Pm[wid][1][0];
        #pragma unroll
        for (int r = 0; r < 4; r++) {
            float p0 = __builtin_amdgcn_exp2f(S0[0][r] * e[0][r]);
            float p1 = __builtin_amdgcn_exp2f(S0[1][r] * e[1][r]);
            float p2 = __builtin_amdgcn_exp2f(S0[2][r] * e[2][r]);
            float p3 = __builtin_amdgcn_exp2f(S0[3][r] * e[3][r]);
            ls0[r] += (p0 + p1) + (p2 + p3);
            uint2 u; u.x = pk2(p0, p1); u.y = pk2(p2, p3);
            *(uint2*)&P0[(quad * 4 + r) * 72 + l15 * 4] = u;
        }
        #pragma unroll
        for (int r = 0; r < 4; r++) {
            float p0 = __builtin_amdgcn_exp2f(S1[0][r] * e[0][r]);
            float p1 = __builtin_amdgcn_exp2f(S1[1][r] * e[1][r]);
            float p2 = __builtin_amdgcn_exp2f(S1[2][r] * e[2][r]);
            float p3 = __builtin_amdgcn_exp2f(S1[3][r] * e[3][r]);
            ls1[r] += (p0 + p1) + (p2 + p3);
            uint2 u; u.x = pk2(p0, p1); u.y = pk2(p2, p3);
            *(uint2*)&P1[(quad * 4 + r) * 72 + l15 * 4] = u;
        }

        #pragma unroll
        for (int ks = 0; ks < 2; ks++) {
            int G = ks * 4 + quad;
            int go = (G ^ (l15 & 7)) * 8;
            bf16x8 a0  = *(const bf16x8*)&P0[l15 * 72 + ks * 32 + quad * 8];
            bf16x8 b00 = *(const bf16x8*)&Vtl[0][l15 * 64 + go];
            bf16x8 b01 = *(const bf16x8*)&Vtl[0][(16 + l15) * 64 + go];
            O00 = __builtin_amdgcn_mfma_f32_16x16x32_bf16(a0, b00, O00, 0, 0, 0);
            O01 = __builtin_amdgcn_mfma_f32_16x16x32_bf16(a0, b01, O01, 0, 0, 0);
            bf16x8 a1  = *(const bf16x8*)&P1[l15 * 72 + ks * 32 + quad * 8];
            bf16x8 b10 = *(const bf16x8*)&Vtl[1][l15 * 64 + go];
            bf16x8 b11 = *(const bf16x8*)&Vtl[1][(16 + l15) * 64 + go];
            O10 = __builtin_amdgcn_mfma_f32_16x16x32_bf16(a1, b10, O10, 0, 0, 0);
            O11 = __builtin_amdgcn_mfma_f32_16x16x32_bf16(a1, b11, O11, 0, 0, 0);
        }
    }

    float* ab  = Opart + (size_t)mz * 2457600 + (size_t)b * 614400;
    float* lsp = lsums + (size_t)mz * 81920;
    #pragma unroll
    for (int r = 0; r < 4; r++) {
        float s0 = ls0[r];
        s0 += __shfl_xor(s0, 1); s0 += __shfl_xor(s0, 2);
        s0 += __shfl_xor(s0, 4); s0 += __shfl_xor(s0, 8);
        float s1 = ls1[r];
        s1 += __shfl_xor(s1, 1); s1 += __shfl_xor(s1, 2);
        s1 += __shfl_xor(s1, 4); s1 += __shfl_xor(s1, 8);
        int lr = myrow + r;
        if (l15 == 0) {
            lsp[bh0 * L + lr] = s0;
            lsp[bh1 * L + lr] = s1;
        }
        size_t base0 = (size_t)h0 * 61440 + (size_t)lr * D30;
        ab[base0 + l15] = O00[r];
        ab[base0 + 61440 + l15] = O10[r];
        if (l15 < 14) {
            ab[base0 + 16 + l15] = O01[r];
            ab[base0 + 61440 + 16 + l15] = O11[r];
        }
    }
}

// ---------------- Combine partials + normalize (in-place on P0) ----------------
__global__ __launch_bounds__(256) void combine_kernel(
    float* __restrict__ P0, const float* __restrict__ lsums, int npart)
{
    int i = blockIdx.x * 256 + threadIdx.x;   // 2,457,600 exact
    float v = P0[i];
    int j = i / 30;
    float s = lsums[j];
    if (npart == 2) { v += P0[2457600 + i]; s += lsums[81920 + j]; }
    P0[i] = v / s;
}

// ---------------- wo -> bf16 padded [256][320] ----------------
__global__ __launch_bounds__(256) void wo16_kernel(
    const float* __restrict__ wo, short* __restrict__ wo16)
{
    int i4 = blockIdx.x * 256 + threadIdx.x;   // 20480 exact
    int idx = i4 * 4;
    int o = idx / 320, c = idx % 320;
    float v0 = (c + 0 < 300) ? wo[o * 300 + c + 0] : 0.f;
    float v1 = (c + 1 < 300) ? wo[o * 300 + c + 1] : 0.f;
    float v2 = (c + 2 < 300) ? wo[o * 300 + c + 2] : 0.f;
    float v3 = (c + 3 < 300) ? wo[o * 300 + c + 3] : 0.f;
    uint2 u; u.x = pk2(v0, v1); u.y = pk2(v2, v3);
    *(uint2*)&wo16[idx] = u;
}

// ---------------- Output projection (bf16 MFMA) ----------------
// out[b, o, m] = bo[o] + sum_c wo[o,c] * ab[c*2048 + m]; tile [64 o x 32 m].
__global__ __launch_bounds__(256, 4) void out_kernel(
    const float* __restrict__ ab4, const short* __restrict__ wo16,
    const float* __restrict__ bo, float* __restrict__ out)
{
    __shared__ __align__(16) short XT[32 * 72];   // [m][c-chunk], stride 72
    const int t    = threadIdx.x;
    const int wid  = t >> 6;
    const int lane = t & 63;
    const int quad = lane >> 4;
    const int l15  = lane & 15;
    const int m0 = blockIdx.x * 32;
    const int o0 = blockIdx.y * 64;
    const int b  = blockIdx.z;
    const float* ab = ab4 + (size_t)b * 614400;

    f32x4 acc0 = {0,0,0,0}, acc1 = {0,0,0,0};
    const int cb = t >> 4;    // 0..15 -> 4 c-rows each
    const int mb = t & 15;    // m pair

    const short* wrow = wo16 + (size_t)(o0 + wid * 16 + l15) * 320;

    for (int cc = 0; cc < 5; cc++) {
        const int c0 = cc * 64;
        __syncthreads();
        {   // stage XT[32 m][64 c] from ab fp32 (clamp rows >=300; W is 0 there)
            int cr0 = c0 + cb * 4;
            float2 r0, r1, r2, r3;
            int a0i = cr0 + 0; a0i = a0i < 300 ? a0i : 299;
            int a1i = cr0 + 1; a1i = a1i < 300 ? a1i : 299;
            int a2i = cr0 + 2; a2i = a2i < 300 ? a2i : 299;
            int a3i = cr0 + 3; a3i = a3i < 300 ? a3i : 299;
            r0 = *(const float2*)(ab + (size_t)a0i * L + m0 + mb * 2);
            r1 = *(const float2*)(ab + (size_t)a1i * L + m0 + mb * 2);
            r2 = *(const float2*)(ab + (size_t)a2i * L + m0 + mb * 2);
            r3 = *(const float2*)(ab + (size_t)a3i * L + m0 + mb * 2);
            uint2 u0; u0.x = pk2(r0.x, r1.x); u0.y = pk2(r2.x, r3.x);
            *(uint2*)&XT[(mb * 2 + 0) * 72 + cb * 4] = u0;
            uint2 u1; u1.x = pk2(r0.y, r1.y); u1.y = pk2(r2.y, r3.y);
            *(uint2*)&XT[(mb * 2 + 1) * 72 + cb * 4] = u1;
        }
        __syncthreads();
        #pragma unroll
        for (int ks = 0; ks < 2; ks++) {
            bf16x8 a  = *(const bf16x8*)(wrow + c0 + ks * 32 + quad * 8);
            bf16x8 b0 = *(const bf16x8*)&XT[l15 * 72 + ks * 32 + quad * 8];
            bf16x8 b1 = *(const bf16x8*)&XT[(16 + l15) * 72 + ks * 32 + quad * 8];
            acc0 = __builtin_amdgcn_mfma_f32_16x16x32_bf16(a, b0, acc0, 0, 0, 0);
            acc1 = __builtin_amdgcn_mfma_f32_16x16x32_bf16(a, b1, acc1, 0, 0, 0);
        }
    }
    #pragma unroll
    for (int r = 0; r < 4; r++) {
        int o = o0 + wid * 16 + quad * 4 + r;
        float bb = bo[o];
        float* orow = out + ((size_t)(b * 256 + o)) * L;
        orow[m0 + l15]      = acc0[r] + bb;
        orow[m0 + 16 + l15] = acc1[r] + bb;
    }
}

extern "C" void kernel_launch(void* const* d_in, const int* in_sizes, int n_in,
                              void* d_out, int out_size, void* d_ws, size_t ws_size,
                              hipStream_t stream) {
    const float* x    = (const float*)d_in[0];
    const float* ax   = (const float*)d_in[1];
    const float* edge = (const float*)d_in[2];
    const float* wq   = (const float*)d_in[3];
    const float* bq   = (const float*)d_in[4];
    const float* wk   = (const float*)d_in[5];
    const float* bk   = (const float*)d_in[6];
    const float* wv   = (const float*)d_in[7];
    const float* bv   = (const float*)d_in[8];
    const float* wo   = (const float*)d_in[9];
    const float* bo   = (const float*)d_in[10];
    float* out = (float*)d_out;

    const size_t KB  = (size_t)4 * NH * L * DP * 2;  // 5,242,880 per bf16 buffer
    const size_t PSZ = (size_t)2457600 * 4;
    const size_t LSZ = (size_t)81920 * 4;
    const size_t WOS = (size_t)256 * 320 * 2;
    char* ws = (char*)d_ws;
    short* Kbuf  = (short*)ws;
    short* Vbuf  = (short*)(ws + KB);
    short* Vtbuf = (short*)(ws + 2 * KB);
    float* P0    = (float*)(ws + 3 * KB);
    int npart = (ws_size >= 3 * KB + 2 * PSZ + 2 * LSZ + WOS) ? 2 : 1;
    float* lsums = (float*)(ws + 3 * KB + (size_t)npart * PSZ);
    short* wo16  = (short*)(ws + 3 * KB + (size_t)npart * (PSZ + LSZ));
    if (ws_size < 3 * KB + PSZ + LSZ + WOS) return;

    hipMemsetAsync(ws, 0, 3 * KB, stream);           // zero pad cols d=30,31

    wo16_kernel<<<dim3(80), 256, 0, stream>>>(wo, wo16);
    proj_kernel<<<dim3(32, 5, 4), 256, 0, stream>>>(x, ax, wq, bq, wk, bk, wv, bv,
                                                    Kbuf, Vbuf, Vtbuf);
    attn_kernel<<<dim3(32, 5, 4 * npart), 256, 0, stream>>>(Kbuf, Vbuf, Vtbuf, edge,
                                                            P0, lsums, npart);
    combine_kernel<<<dim3(9600), 256, 0, stream>>>(P0, lsums, npart);
    out_kernel<<<dim3(64, 4, 4), 256, 0, stream>>>(P0, wo16, bo, out);
}

// Round 5
// 221.060 us; speedup vs baseline: 1.9218x; 1.0366x over previous
//
#include <hip/hip_runtime.h>
#include <hip/hip_bf16.h>
#include <math.h>

#define L 2048
#define NH 10
#define DP 32
#define D30 30

typedef __attribute__((ext_vector_type(8))) short bf16x8;
typedef __attribute__((ext_vector_type(4))) float f32x4;

__device__ inline short f2bf(float f) {
    union { float f; unsigned u; } v; v.f = f;
    unsigned r = (v.u + 0x7FFF + ((v.u >> 16) & 1)) >> 16;
    return (short)r;
}
// pack two floats to bf16x2 (round-half-up)
__device__ inline unsigned pk2(float a, float b) {
    unsigned ua = __float_as_uint(a) + 0x8000u;
    unsigned ub = __float_as_uint(b) + 0x8000u;
    return (ua >> 16) | (ub & 0xFFFF0000u);
}
// K-order permutation within 64-chunks (shared by P-tile and Vt layout)
__device__ inline int permL(int l) {
    return (l & ~63) | ((l & 15) << 2) | ((l >> 4) & 3);
}

#define GLD16(g, l) __builtin_amdgcn_global_load_lds( \
    (__attribute__((address_space(1))) void*)(g),     \
    (__attribute__((address_space(3))) void*)(l), 16, 0, 0)

// ---------------- Projection kernel (bf16 MFMA) + wo16 conversion (og=5) ------
__global__ __launch_bounds__(256) void proj_kernel(
    const float* __restrict__ x, const float* __restrict__ ax,
    const float* __restrict__ wq, const float* __restrict__ bq,
    const float* __restrict__ wk, const float* __restrict__ bk,
    const float* __restrict__ wv, const float* __restrict__ bv,
    const float* __restrict__ wo, short* __restrict__ wo16,
    short* __restrict__ Kbuf, short* __restrict__ Vbuf, short* __restrict__ Vtbuf)
{
    const int t  = threadIdx.x;
    const int og = blockIdx.y;       // 0..4 proj, 5 = wo16 conversion
    const int b  = blockIdx.z;

    if (og == 5) {                   // wo -> bf16 padded [256][320]
        int id = (b * 32 + blockIdx.x) * 256 + t;
        if (id < 20480) {
            int idx = id * 4;
            int o = idx / 320, c = idx % 320;
            float v0 = (c + 0 < 300) ? wo[o * 300 + c + 0] : 0.f;
            float v1 = (c + 1 < 300) ? wo[o * 300 + c + 1] : 0.f;
            float v2 = (c + 2 < 300) ? wo[o * 300 + c + 2] : 0.f;
            float v3 = (c + 3 < 300) ? wo[o * 300 + c + 3] : 0.f;
            uint2 u; u.x = pk2(v0, v1); u.y = pk2(v2, v3);
            *(uint2*)&wo16[idx] = u;
        }
        return;
    }

    __shared__ __align__(16) short Wl[112 * 72];   // [o][64c], stride 72 (pad)
    __shared__ __align__(16) short XT[64 * 72];    // [l][64c], stride 72
    const int l0 = blockIdx.x * 64;

    const float* W; const float* bias;
    if (og == 0)      { W = wq; bias = bq; }
    else if (og <= 2) { W = wk; bias = bk; }
    else              { W = wv; bias = bv; }
    const int al = (og - 1) & 1;

    const int wid  = t >> 6;
    const int lane = t & 63;
    const int quad = lane >> 4;
    const int l15  = lane & 15;

    f32x4 acc[7];
    #pragma unroll
    for (int ot = 0; ot < 7; ot++) acc[ot] = (f32x4){0,0,0,0};

    const int cq = (t & 15) * 4;    // c-quad for X staging
    const int lq = (t >> 4) * 4;    // l-quad for X staging
    const size_t rs = (og == 0) ? (size_t)L : (size_t)(2 * L);  // c-row stride

    for (int cc = 0; cc < 4; cc++) {
        const int c0 = cc * 64;
        __syncthreads();
        #pragma unroll
        for (int it = 0; it < 7; it++) {
            int kk = (t + it * 256) * 4;
            int o = kk >> 6, c = kk & 63;
            f32x4 v = {0, 0, 0, 0};
            if (o < 100) v = *(const f32x4*)(W + (size_t)o * 256 + c0 + c);
            uint2 u; u.x = pk2(v[0], v[1]); u.y = pk2(v[2], v[3]);
            *(uint2*)&Wl[o * 72 + c] = u;
        }
        {
            const float* src = (og == 0)
                ? x  + ((size_t)(b * 256 + c0 + cq)) * L + l0 + lq
                : ax + (((size_t)(b * 256 + c0 + cq)) * 2 + al) * L + l0 + lq;
            f32x4 r0 = *(const f32x4*)(src);
            f32x4 r1 = *(const f32x4*)(src + rs);
            f32x4 r2 = *(const f32x4*)(src + 2 * rs);
            f32x4 r3 = *(const f32x4*)(src + 3 * rs);
            #pragma unroll
            for (int i = 0; i < 4; i++) {
                uint2 u; u.x = pk2(r0[i], r1[i]); u.y = pk2(r2[i], r3[i]);
                *(uint2*)&XT[(lq + i) * 72 + cq] = u;
            }
        }
        __syncthreads();
        #pragma unroll
        for (int ks = 0; ks < 2; ks++) {
            bf16x8 bfrag = *(const bf16x8*)&XT[(wid * 16 + l15) * 72 + ks * 32 + quad * 8];
            #pragma unroll
            for (int ot = 0; ot < 7; ot++) {
                bf16x8 afrag = *(const bf16x8*)&Wl[(ot * 16 + l15) * 72 + ks * 32 + quad * 8];
                acc[ot] = __builtin_amdgcn_mfma_f32_16x16x32_bf16(afrag, bfrag, acc[ot], 0, 0, 0);
            }
        }
    }

    const int part = (og == 0) ? 0 : ((og == 1 || og == 3) ? 1 : 2);
    const float KS = 0.31622776601683794f * 1.4426950408889634f;  // scale*log2e
    const int l = l0 + wid * 16 + l15;
    #pragma unroll
    for (int ot = 0; ot < 7; ot++) {
        #pragma unroll
        for (int r = 0; r < 4; r++) {
            int o = ot * 16 + quad * 4 + r;
            if (o >= 100) continue;
            float val = acc[ot][r] + bias[o];
            int h = o / 10, dd = 3 * (o % 10) + part;
            size_t rowb = ((size_t)(b * NH + h)) * L;
            size_t tb   = ((size_t)(b * NH + h) * DP + dd) * L;
            if (og == 0) {
                Kbuf[(rowb + l) * DP + dd] = f2bf(val * KS);
                short s = f2bf(val);
                Vbuf[(rowb + l) * DP + dd] = s;
                Vtbuf[tb + permL(l)] = s;
            } else if (og <= 2) {
                Kbuf[(rowb + l) * DP + dd] = f2bf(val * KS);
            } else {
                short s = f2bf(val);
                Vbuf[(rowb + l) * DP + dd] = s;
                Vtbuf[tb + permL(l)] = s;
            }
        }
    }
}

// ---------------- Flash attention: seq-head P reuse, 25.6 KB LDS, XCD swizzle -
// 1D grid, id = gg*40 + h2*8 + xcd: the 5 h-pairs sharing one (b,l0,mz) edge
// tile share id%8 -> same XCD L2. 5 blocks/CU resident, tail-free.
__global__ __launch_bounds__(256, 5) void attn_kernel(
    const short* __restrict__ K, const short* __restrict__ V,
    const short* __restrict__ Vt, const float* __restrict__ edge,
    float* __restrict__ Opart, float* __restrict__ lsums, int npart)
{
    __shared__ __align__(16) short Vl[2][64 * 32];    // [head][m][d swizzled]  8 KB
    __shared__ __align__(16) short Vtl[2][32 * 64];   // [head][d][m swizzled]  8 KB
    __shared__ __align__(16) short Pm[4][16 * 72];    // per-wave P tile        9 KB
    const int t    = threadIdx.x;
    const int wid  = t >> 6;
    const int lane = t & 63;
    const int quad = lane >> 4;
    const int l15  = lane & 15;

    const int id  = blockIdx.x;
    const int gg  = id / 40;
    const int rem = id - gg * 40;
    const int h2  = rem >> 3;
    const int g   = gg * 8 + (rem & 7);
    const int lb  = g & 31;
    const int b   = (g >> 5) & 3;
    const int mz  = g >> 7;

    const int l0 = lb * 64;
    const int h0 = h2 * 2;
    const size_t bh0 = (size_t)(b * NH + h0), bh1 = bh0 + 1;
    const int mbase = mz * (L / npart);
    const int nit   = (L / npart) / 64;

    const int lrow = l0 + wid * 16 + l15;
    bf16x8 kf[2];
    kf[0] = *(const bf16x8*)(K + (bh0 * L + lrow) * DP + quad * 8);
    kf[1] = *(const bf16x8*)(K + (bh1 * L + lrow) * DP + quad * 8);

    const int myrow = l0 + wid * 16 + quad * 4;
    const float* ep[4];
    #pragma unroll
    for (int r = 0; r < 4; r++)
        ep[r] = edge + (size_t)b * L * L + (size_t)(myrow + r) * L + l15 + mbase;

    // staging pointer: waves 0,1 stage V (head wid&1); waves 2,3 stage Vt
    const int sh = wid & 1;
    const size_t sbh = bh0 + sh;
    const short* sgp;
    if (wid < 2)
        sgp = V + (sbh * L + mbase + (lane >> 2)) * DP + (((lane & 3) ^ ((lane >> 3) & 3)) * 8);
    else
        sgp = Vt + (sbh * DP + (lane >> 3)) * L + mbase + (((lane & 7) ^ ((lane >> 3) & 7)) * 8);

    float ls[2][4] = {{0,0,0,0},{0,0,0,0}};
    f32x4 O[2][2] = {{{0,0,0,0},{0,0,0,0}},{{0,0,0,0},{0,0,0,0}}};
    const f32x4 z = {0,0,0,0};

    for (int mt = 0; mt < nit; mt++) {
        __syncthreads();                     // prior LDS reads done
        if (wid < 2) {
            #pragma unroll
            for (int k = 0; k < 4; k++)
                GLD16(sgp + k * (16 * DP), &Vl[sh][k * 512]);
        } else {
            #pragma unroll
            for (int k = 0; k < 4; k++)
                GLD16(sgp + (size_t)k * (8 * L), &Vtl[sh][k * 512]);
        }
        float e[4][4];
        #pragma unroll
        for (int r = 0; r < 4; r++)
            #pragma unroll
            for (int nb = 0; nb < 4; nb++)
                e[nb][r] = ep[r][nb * 16];
        __syncthreads();                     // tiles + edge ready

        short* P = &Pm[wid][0];
        #pragma unroll
        for (int hh = 0; hh < 2; hh++) {
            f32x4 S[4];
            #pragma unroll
            for (int nb = 0; nb < 4; nb++) {
                int sw = (quad ^ ((l15 >> 1) & 3)) * 8;
                bf16x8 vf = *(const bf16x8*)&Vl[hh][(nb * 16 + l15) * 32 + sw];
                S[nb] = __builtin_amdgcn_mfma_f32_16x16x32_bf16(kf[hh], vf, z, 0, 0, 0);
            }
            #pragma unroll
            for (int r = 0; r < 4; r++) {
                float p0 = __builtin_amdgcn_exp2f(S[0][r] * e[0][r]);
                float p1 = __builtin_amdgcn_exp2f(S[1][r] * e[1][r]);
                float p2 = __builtin_amdgcn_exp2f(S[2][r] * e[2][r]);
                float p3 = __builtin_amdgcn_exp2f(S[3][r] * e[3][r]);
                ls[hh][r] += (p0 + p1) + (p2 + p3);
                uint2 u; u.x = pk2(p0, p1); u.y = pk2(p2, p3);
                *(uint2*)&P[(quad * 4 + r) * 72 + l15 * 4] = u;   // k' = l15*4+nb
            }
            #pragma unroll
            for (int ks = 0; ks < 2; ks++) {
                int go = ((ks * 4 + quad) ^ (l15 & 7)) * 8;
                bf16x8 a  = *(const bf16x8*)&P[l15 * 72 + ks * 32 + quad * 8];
                bf16x8 b0 = *(const bf16x8*)&Vtl[hh][l15 * 64 + go];
                bf16x8 b1 = *(const bf16x8*)&Vtl[hh][(16 + l15) * 64 + go];
                O[hh][0] = __builtin_amdgcn_mfma_f32_16x16x32_bf16(a, b0, O[hh][0], 0, 0, 0);
                O[hh][1] = __builtin_amdgcn_mfma_f32_16x16x32_bf16(a, b1, O[hh][1], 0, 0, 0);
            }
        }
        #pragma unroll
        for (int r = 0; r < 4; r++) ep[r] += 64;
        sgp += (wid < 2) ? 64 * DP : 64;
    }

    // epilogue: UNNORMALIZED O partial + lsum
    float* ab  = Opart + (size_t)mz * 2457600 + (size_t)b * 614400;
    float* lsp = lsums + (size_t)mz * 81920 + (size_t)b * 20480;
    #pragma unroll
    for (int r = 0; r < 4; r++) {
        float s0 = ls[0][r];
        s0 += __shfl_xor(s0, 1); s0 += __shfl_xor(s0, 2);
        s0 += __shfl_xor(s0, 4); s0 += __shfl_xor(s0, 8);
        float s1 = ls[1][r];
        s1 += __shfl_xor(s1, 1); s1 += __shfl_xor(s1, 2);
        s1 += __shfl_xor(s1, 4); s1 += __shfl_xor(s1, 8);
        int lr = myrow + r;
        if (l15 == 0) {
            lsp[h0 * L + lr]       = s0;
            lsp[(h0 + 1) * L + lr] = s1;
        }
        size_t base0 = (size_t)h0 * 61440 + (size_t)lr * D30;
        ab[base0 + l15]         = O[0][0][r];
        ab[base0 + 61440 + l15] = O[1][0][r];
        if (l15 < 14) {
            ab[base0 + 16 + l15]         = O[0][1][r];
            ab[base0 + 61440 + 16 + l15] = O[1][1][r];
        }
    }
}

// ---------------- Output projection (bf16 MFMA) with fused combine ------------
// out[b,o,m] = bo[o] + sum_c wo[o,c] * ((P0[f]+P1[f]) / (ls0[f/30]+ls1[f/30])),
// f = c*2048+m (torch-view flat index within batch).
__global__ __launch_bounds__(256, 4) void out_kernel(
    const float* __restrict__ Opart, const float* __restrict__ lsums,
    const short* __restrict__ wo16, const float* __restrict__ bo,
    float* __restrict__ out, int npart)
{
    __shared__ __align__(16) short XT[32 * 72];   // [m][c-chunk], stride 72
    const int t    = threadIdx.x;
    const int wid  = t >> 6;
    const int lane = t & 63;
    const int quad = lane >> 4;
    const int l15  = lane & 15;
    const int m0 = blockIdx.x * 32;
    const int o0 = blockIdx.y * 64;
    const int b  = blockIdx.z;
    const float* P0b = Opart + (size_t)b * 614400;
    const float* P1b = Opart + 2457600 + (size_t)b * 614400;
    const float* ls0 = lsums + (size_t)b * 20480;
    const float* ls1 = lsums + 81920 + (size_t)b * 20480;

    f32x4 acc0 = {0,0,0,0}, acc1 = {0,0,0,0};
    const int cb = t >> 4;    // 0..15 -> 4 c-rows each
    const int mb = t & 15;    // m pair
    const short* wrow = wo16 + (size_t)(o0 + wid * 16 + l15) * 320;

    for (int cc = 0; cc < 5; cc++) {
        const int c0 = cc * 64;
        __syncthreads();
        {   // stage XT[32 m][64 c]: partial-sum + normalize + bf16 pack
            int crb = c0 + cb * 4;
            float vx[4], vy[4];
            #pragma unroll
            for (int i = 0; i < 4; i++) {
                int cr = crb + i; if (cr > 299) cr = 299;  // W rows >=300 are 0
                int f = cr * 2048 + m0 + mb * 2;
                float2 p = *(const float2*)(P0b + f);
                int j0 = f / 30, j1 = (f + 1) / 30;
                float s0 = ls0[j0], s1 = ls0[j1];
                if (npart == 2) {
                    float2 q = *(const float2*)(P1b + f);
                    p.x += q.x; p.y += q.y;
                    s0 += ls1[j0]; s1 += ls1[j1];
                }
                vx[i] = p.x * __builtin_amdgcn_rcpf(s0);
                vy[i] = p.y * __builtin_amdgcn_rcpf(s1);
            }
            uint2 u0; u0.x = pk2(vx[0], vx[1]); u0.y = pk2(vx[2], vx[3]);
            *(uint2*)&XT[(mb * 2 + 0) * 72 + cb * 4] = u0;
            uint2 u1; u1.x = pk2(vy[0], vy[1]); u1.y = pk2(vy[2], vy[3]);
            *(uint2*)&XT[(mb * 2 + 1) * 72 + cb * 4] = u1;
        }
        __syncthreads();
        #pragma unroll
        for (int ks = 0; ks < 2; ks++) {
            bf16x8 a  = *(const bf16x8*)(wrow + c0 + ks * 32 + quad * 8);
            bf16x8 b0 = *(const bf16x8*)&XT[l15 * 72 + ks * 32 + quad * 8];
            bf16x8 b1 = *(const bf16x8*)&XT[(16 + l15) * 72 + ks * 32 + quad * 8];
            acc0 = __builtin_amdgcn_mfma_f32_16x16x32_bf16(a, b0, acc0, 0, 0, 0);
            acc1 = __builtin_amdgcn_mfma_f32_16x16x32_bf16(a, b1, acc1, 0, 0, 0);
        }
    }
    #pragma unroll
    for (int r = 0; r < 4; r++) {
        int o = o0 + wid * 16 + quad * 4 + r;
        float bb = bo[o];
        float* orow = out + ((size_t)(b * 256 + o)) * L;
        orow[m0 + l15]      = acc0[r] + bb;
        orow[m0 + 16 + l15] = acc1[r] + bb;
    }
}

extern "C" void kernel_launch(void* const* d_in, const int* in_sizes, int n_in,
                              void* d_out, int out_size, void* d_ws, size_t ws_size,
                              hipStream_t stream) {
    const float* x    = (const float*)d_in[0];
    const float* ax   = (const float*)d_in[1];
    const float* edge = (const float*)d_in[2];
    const float* wq   = (const float*)d_in[3];
    const float* bq   = (const float*)d_in[4];
    const float* wk   = (const float*)d_in[5];
    const float* bk   = (const float*)d_in[6];
    const float* wv   = (const float*)d_in[7];
    const float* bv   = (const float*)d_in[8];
    const float* wo   = (const float*)d_in[9];
    const float* bo   = (const float*)d_in[10];
    float* out = (float*)d_out;

    const size_t KB  = (size_t)4 * NH * L * DP * 2;  // 5,242,880 per bf16 buffer
    const size_t PSZ = (size_t)2457600 * 4;
    const size_t LSZ = (size_t)81920 * 4;
    const size_t WOS = (size_t)256 * 320 * 2;
    char* ws = (char*)d_ws;
    short* Kbuf  = (short*)ws;
    short* Vbuf  = (short*)(ws + KB);
    short* Vtbuf = (short*)(ws + 2 * KB);
    float* P0    = (float*)(ws + 3 * KB);
    int npart = (ws_size >= 3 * KB + 2 * PSZ + 2 * LSZ + WOS) ? 2 : 1;
    float* lsums = (float*)(ws + 3 * KB + (size_t)npart * PSZ);
    short* wo16  = (short*)(ws + 3 * KB + (size_t)npart * (PSZ + LSZ));
    if (ws_size < 3 * KB + PSZ + LSZ + WOS) return;

    hipMemsetAsync(ws, 0, 3 * KB, stream);           // zero pad cols d=30,31

    proj_kernel<<<dim3(32, 6, 4), 256, 0, stream>>>(x, ax, wq, bq, wk, bk, wv, bv,
                                                    wo, wo16, Kbuf, Vbuf, Vtbuf);
    attn_kernel<<<dim3(640 * npart), 256, 0, stream>>>(Kbuf, Vbuf, Vtbuf, edge,
                                                       P0, lsums, npart);
    out_kernel<<<dim3(64, 4, 4), 256, 0, stream>>>(P0, lsums, wo16, bo, out, npart);
}